// Round 9
// baseline (266.100 us; speedup 1.0000x reference)
//
#include <hip/hip_runtime.h>

// KinematicWaveRouting: outlet(t) = basin_area*50 * sum_k w[k]*runoff(t-k),
// w[k] = P(Binom(k,0.9) <= 19): exactly 1.0 for k<=19 (box part, slid),
// fast decay after; K=32 taps.
//
// R10 -> R11: R10's pad+NT both failed their counters (conflicts 8->9.7e6,
// WRITE inflated 134->147MB); reverted. R8's profile shows wall ~= SUM of
// HBM(33us)+LDS(26us)+VALU(17us) with nothing saturated, and overlap
// attempts (R9/R10) were neutral. So cut the LDS phase by construction:
// RPT 8->32 (TPB 128). Per thread: 9 history + 8 streamed quads = 16
// ds_read_b128 per 8 output quads -> LDS read amplification 5x -> 2x.
// Lane read stride becomes 8 quads; pad pidx(q)=q+q/8 makes it stride 9 ->
// each 8-lane b128 phase hits all 8 bank groups once (staging write:
// multiplicity 2 = free). Box+tail FIR identical to R8, restructured as a
// rolling 36-float window (fully unrolled -> compile-time indices only).

#define KTAPS 32
#define RPT   32                     // outputs per thread along t
#define TPB   128
#define TILE_T (TPB * RPT)           // 4096 t-values per tile (= one row)
#define NQ   ((TILE_T + KTAPS) / 4)  // 1032 staged quads incl. 32-halo
#define NQP  (NQ + NQ / 8)           // 1161 padded slots (18.6 KB)

struct WTab { float w[KTAPS]; };

__device__ __forceinline__ int pidx(int q) { return q + (q >> 3); }

__global__ __launch_bounds__(TPB) void kwr_fir_lds_kernel(
    const float* __restrict__ runoff,
    const float* __restrict__ basin_area,
    float* __restrict__ out,
    int T, int tiles_per_row, WTab wt)
{
    __shared__ float4 lds[NQP];

    const int tid  = threadIdx.x;
    const int blk  = blockIdx.x;
    const int b    = blk / tiles_per_row;
    const int tile = blk - b * tiles_per_row;
    const long long rowbase = (long long)b * T;
    const int tstart = tile * TILE_T - KTAPS;  // global t of LDS float 0

    const float s = basin_area[b] * 50.0f;     // (1e6/1000/3600/20) * DT

    // ---- stage tile (coalesced float4 loads, padded LDS write) ------------
    const float4* gsrc = (const float4*)(runoff + rowbase + tstart);
    #pragma unroll
    for (int p = 0; p < (NQ + TPB - 1) / TPB; ++p) {   // 9 passes
        int q = tid + p * TPB;
        if (q < NQ) {
            float4 v;
            if (tstart + 4 * q >= 0) v = gsrc[q];      // in-row (halo ok)
            else                     v = make_float4(0.f, 0.f, 0.f, 0.f);
            lds[pidx(q)] = v;
        }
    }
    __syncthreads();

    // ---- rolling-window FIR: 32 outputs per thread ------------------------
    // Thread base LDS float jb = 32*tid; outputs t = 32*tid + r (r=0..31)
    // live at LDS float jb+32+r. Tap k reads LDS float jb+32+r-k.
    // Window for group g (r=4g..4g+3): win[m] = LDS float jb+4g+m, m=0..35.
    //   box  (k<=19): S(r) = sum floats jb+13+r..jb+32+r; slide by +/-1.
    //   tail (k=20..31): float jb+32+r-k = win[(r-4g)+32-k] in [0..15].
    const int qb = 8 * tid;                    // first LDS quad of window

    float win[36];
    #pragma unroll
    for (int c = 0; c < 9; ++c) {              // quads qb..qb+8 -> win[0..35]
        float4 v = lds[pidx(qb + c)];
        win[4*c+0] = v.x; win[4*c+1] = v.y;
        win[4*c+2] = v.z; win[4*c+3] = v.w;
    }

    float S = 0.0f;                            // S(r=0): floats jb+13..jb+32
    #pragma unroll
    for (int m = 13; m <= 32; ++m) S += win[m];

    float4* orow = (float4*)(out + rowbase + (long long)tile * TILE_T) + qb;

    #pragma unroll
    for (int g = 0; g < 8; ++g) {
        // next quad (floats jb+4g+36..39); not needed for the last group
        float4 nv = make_float4(0.f, 0.f, 0.f, 0.f);
        if (g < 7) nv = lds[pidx(qb + 9 + g)];

        float a[4];
        #pragma unroll
        for (int ss = 0; ss < 4; ++ss) {
            float acc = S;
            #pragma unroll
            for (int k = 20; k < KTAPS; ++k)   // tail taps
                acc = fmaf(wt.w[k], win[ss + 32 - k], acc);
            a[ss] = acc * s;
            if (ss < 3)                        // slide S to r+1 (in-window)
                S += win[33 + ss] - win[13 + ss];
        }
        orow[g] = make_float4(a[0], a[1], a[2], a[3]);

        // shift window by one quad and finish the cross-quad slide
        if (g < 7) {
            #pragma unroll
            for (int m = 0; m < 32; ++m) win[m] = win[m + 4];
            win[32] = nv.x; win[33] = nv.y; win[34] = nv.z; win[35] = nv.w;
            S += win[32] - win[12];            // r=4g+3 -> 4g+4
        }
    }
}

extern "C" void kernel_launch(void* const* d_in, const int* in_sizes, int n_in,
                              void* d_out, int out_size, void* d_ws, size_t ws_size,
                              hipStream_t stream)
{
    const float* runoff     = (const float*)d_in[0];
    const float* basin_area = (const float*)d_in[1];
    float* out = (float*)d_out;

    const int B = in_sizes[1];            // basin_area has B elements
    const int T = in_sizes[0] / B;        // runoff is (B, T)

    // Impulse response of the linear recurrence, computed in double.
    WTab wt;
    double Q[21];
    for (int j = 0; j <= 20; ++j) Q[j] = (j >= 1) ? 1.0 : 0.0;
    wt.w[0] = 1.0f;
    for (int k = 1; k < KTAPS; ++k) {
        for (int j = 20; j >= 1; --j) Q[j] = 0.1 * Q[j] + 0.9 * Q[j - 1];
        wt.w[k] = (float)Q[20];
    }

    const int tiles_per_row = T / TILE_T;           // 4096/4096 = 1
    const int nblk = B * tiles_per_row;             // 8192

    kwr_fir_lds_kernel<<<nblk, TPB, 0, stream>>>(runoff, basin_area, out,
                                                 T, tiles_per_row, wt);
}